// Round 4
// baseline (190.238 us; speedup 1.0000x reference)
//
#include <hip/hip_runtime.h>

#define NB 8192
#define NT 64
#define FCAP 5.0f

typedef unsigned int u32;
typedef float f32x16 __attribute__((ext_vector_type(16)));
typedef float f32x4 __attribute__((ext_vector_type(4)));
typedef __bf16 bf16x8 __attribute__((ext_vector_type(8)));
typedef u32 u32x4 __attribute__((ext_vector_type(4)));

static __device__ __forceinline__ u32 pk2(float lo, float hi) {
  u32 r;
  asm("v_cvt_pk_bf16_f32 %0, %1, %2" : "=v"(r) : "v"(lo), "v"(hi));
  return r;
}
static __device__ __forceinline__ float clipc(float a) { return fminf(fmaxf(a, -FCAP), FCAP); }

// pack 8 consecutive f32 into one bf16x8 A-fragment (RNE)
static __device__ __forceinline__ bf16x8 mkfrag(const float* __restrict__ p) {
  f32x4 a = *(const f32x4*)p, b = *(const f32x4*)(p + 4);
  u32x4 wv = {pk2(a[0], a[1]), pk2(a[2], a[3]), pk2(b[0], b[1]), pk2(b[2], b[3])};
  return __builtin_bit_cast(bf16x8, wv);
}

// 32x32x16 bf16 layouts (HW-verified in round 3):
//   A: row = lane&31, k = 16*kt + 8*(lane>>5) + e
//   B: col = lane&31, k = 16*kt + 8*(lane>>5) + e
//   C: col = lane&31, row = (r&3) + 8*(r>>2) + 4*(lane>>5)
// FIX8: C regs q..q+7 (16 rows) -> 4 B-frag words via cvt_pk + permlane32_swap
#define FIX8(C, q, r0, r1, r2, r3)                                        \
  {                                                                       \
    u32 X0 = pk2(C[q + 0], C[q + 1]), X1 = pk2(C[q + 2], C[q + 3]);       \
    u32 Y0 = pk2(C[q + 4], C[q + 5]), Y1 = pk2(C[q + 6], C[q + 7]);       \
    auto s0 = __builtin_amdgcn_permlane32_swap(X0, Y0, false, false);     \
    auto s1 = __builtin_amdgcn_permlane32_swap(X1, Y1, false, false);     \
    r0 = s0[0]; r1 = s1[0]; r2 = s0[1]; r3 = s1[1];                       \
  }

// leaky_relu as 2 ops: max(x, 0.01*x)
#define LRELU16(C)                                                        \
  _Pragma("unroll") for (int r_ = 0; r_ < 16; ++r_) {                     \
    C[r_] = fmaxf(C[r_], 0.01f * C[r_]);                                  \
  }

// 256 WGs x 256 threads. Each wave independently integrates 8 particles with
// the FULL MLP held in registers (bf16 A-frags). No LDS, no barriers. The 4x
// column waste (8 of 32 MFMA cols used) buys zero inter-wave communication.
__global__ __launch_bounds__(256, 1) void ode_kernel(
    const float* __restrict__ ts, const float* __restrict__ y0,
    const float* __restrict__ W1, const float* __restrict__ b1,
    const float* __restrict__ W2, const float* __restrict__ b2,
    const float* __restrict__ W3, const float* __restrict__ b3,
    const float* __restrict__ W4, const float* __restrict__ b4,
    float* __restrict__ out) {
  const int l = threadIdx.x & 63;
  const int w = threadIdx.x >> 6;
  const int h = l >> 5;
  const int row = l & 31;                      // A-row / B-col / particle slot
  const int p = blockIdx.x * 32 + w * 8 + row; // particle (valid if row<8)

  // ---- weight fragments (one-time, f32 -> bf16 RNE) ----
  bf16x8 aW2[4][8], aW3[4][8];
#pragma unroll
  for (int m = 0; m < 4; ++m) {
#pragma unroll
    for (int kt = 0; kt < 8; ++kt) {
      aW2[m][kt] = mkfrag(W2 + (32 * m + row) * 128 + 16 * kt + 8 * h);
      aW3[m][kt] = mkfrag(W3 + (32 * m + row) * 128 + 16 * kt + 8 * h);
    }
  }
  // L1: K=2 real + bias at k=2 (B supplies y1,y2,1)
  bf16x8 aW1[4], aB2[4], aB3[4];
#pragma unroll
  for (int m = 0; m < 4; ++m) {
    u32x4 f1 = {0, 0, 0, 0}, f2 = {0, 0, 0, 0}, f3 = {0, 0, 0, 0};
    if (h == 0) {
      const int r = 32 * m + row;
      f1[0] = pk2(W1[r * 2], W1[r * 2 + 1]);
      f1[1] = pk2(b1[r], 0.f);
      f2[0] = pk2(b2[r], 0.f);
      f3[0] = pk2(b3[r], 0.f);
    }
    aW1[m] = __builtin_bit_cast(bf16x8, f1);
    aB2[m] = __builtin_bit_cast(bf16x8, f2);
    aB3[m] = __builtin_bit_cast(bf16x8, f3);
  }
  // L4: A rows 0,1 = W4, rest zero
  bf16x8 aW4[8];
#pragma unroll
  for (int kt = 0; kt < 8; ++kt) {
    u32x4 f = {0, 0, 0, 0};
    if (row < 2) {
      const float* s = W4 + row * 128 + 16 * kt + 8 * h;
      f32x4 a = *(const f32x4*)s, b = *(const f32x4*)(s + 4);
      f = (u32x4){pk2(a[0], a[1]), pk2(a[2], a[3]), pk2(b[0], b[1]), pk2(b[2], b[3])};
    }
    aW4[kt] = __builtin_bit_cast(bf16x8, f);
  }
  const float b40 = b4[0], b41 = b4[1];

  // B "ones" fragment: k=0 -> 1.0 (for bias tiles)
  u32x4 onesw = {0, 0, 0, 0};
  if (h == 0) onesw[0] = 0x3f80u;  // bf16(1.0)
  const bf16x8 Bones = __builtin_bit_cast(bf16x8, onesw);

  f32x16 zero16 = {0.f, 0.f, 0.f, 0.f, 0.f, 0.f, 0.f, 0.f,
                   0.f, 0.f, 0.f, 0.f, 0.f, 0.f, 0.f, 0.f};

  // ---- state (valid in lanes row<8; h==0 half is authoritative) ----
  float y1 = 0.f, y2 = 0.f;
  if (row < 8) {
    y1 = y0[p * 2];
    y2 = y0[p * 2 + 1];
  }
  if (h == 0 && row < 8) {
    float2 st = {clipc(y1), clipc(y2)};
    *(float2*)(out + p * 2) = st;
  }

#pragma unroll 1
  for (int t = 0; t < NT - 1; ++t) {
    const float dt = ts[t + 1] - ts[t];

    // B for layer 1: k0=y1, k1=y2, k2=1.0 (bias)
    u32x4 byw = {0, 0, 0, 0};
    if (h == 0) {
      byw[0] = pk2(y1, y2);
      byw[1] = 0x3f80u;
    }
    const bf16x8 By = __builtin_bit_cast(bf16x8, byw);

    f32x16 C[4];
    u32x4 hb[8];

    // ---- layer 1 (W1,b1 fused in one k-tile) ----
#pragma unroll
    for (int m = 0; m < 4; ++m)
      C[m] = __builtin_amdgcn_mfma_f32_32x32x16_bf16(aW1[m], By, zero16, 0, 0, 0);
#pragma unroll
    for (int m = 0; m < 4; ++m) {
      LRELU16(C[m]);
      FIX8(C[m], 0, hb[2 * m][0], hb[2 * m][1], hb[2 * m][2], hb[2 * m][3]);
      FIX8(C[m], 8, hb[2 * m + 1][0], hb[2 * m + 1][1], hb[2 * m + 1][2], hb[2 * m + 1][3]);
    }

    // ---- layer 2 ----
#pragma unroll
    for (int m = 0; m < 4; ++m) {
      C[m] = __builtin_amdgcn_mfma_f32_32x32x16_bf16(aB2[m], Bones, zero16, 0, 0, 0);
#pragma unroll
      for (int kt = 0; kt < 8; ++kt)
        C[m] = __builtin_amdgcn_mfma_f32_32x32x16_bf16(
            aW2[m][kt], __builtin_bit_cast(bf16x8, hb[kt]), C[m], 0, 0, 0);
    }
#pragma unroll
    for (int m = 0; m < 4; ++m) {
      LRELU16(C[m]);
      FIX8(C[m], 0, hb[2 * m][0], hb[2 * m][1], hb[2 * m][2], hb[2 * m][3]);
      FIX8(C[m], 8, hb[2 * m + 1][0], hb[2 * m + 1][1], hb[2 * m + 1][2], hb[2 * m + 1][3]);
    }

    // ---- layer 3 ----
#pragma unroll
    for (int m = 0; m < 4; ++m) {
      C[m] = __builtin_amdgcn_mfma_f32_32x32x16_bf16(aB3[m], Bones, zero16, 0, 0, 0);
#pragma unroll
      for (int kt = 0; kt < 8; ++kt)
        C[m] = __builtin_amdgcn_mfma_f32_32x32x16_bf16(
            aW3[m][kt], __builtin_bit_cast(bf16x8, hb[kt]), C[m], 0, 0, 0);
    }
#pragma unroll
    for (int m = 0; m < 4; ++m) {
      LRELU16(C[m]);
      FIX8(C[m], 0, hb[2 * m][0], hb[2 * m][1], hb[2 * m][2], hb[2 * m][3]);
      FIX8(C[m], 8, hb[2 * m + 1][0], hb[2 * m + 1][1], hb[2 * m + 1][2], hb[2 * m + 1][3]);
    }

    // ---- layer 4: f rows 0,1 land in C4[0],C4[1] at h==0 ----
    f32x16 C4 = __builtin_amdgcn_mfma_f32_32x32x16_bf16(
        aW4[0], __builtin_bit_cast(bf16x8, hb[0]), zero16, 0, 0, 0);
#pragma unroll
    for (int kt = 1; kt < 8; ++kt)
      C4 = __builtin_amdgcn_mfma_f32_32x32x16_bf16(
          aW4[kt], __builtin_bit_cast(bf16x8, hb[kt]), C4, 0, 0, 0);

    const float f0 = C4[0] + b40;
    const float f1v = C4[1] + b41;
    y1 += dt * (f0 - y1);
    y2 += dt * (f1v - y2);

    if (h == 0 && row < 8) {
      float2 st = {clipc(y1), clipc(y2)};
      *(float2*)(out + (t + 1) * (NB * 2) + p * 2) = st;
    }
  }
}

extern "C" void kernel_launch(void* const* d_in, const int* in_sizes, int n_in,
                              void* d_out, int out_size, void* d_ws, size_t ws_size,
                              hipStream_t stream) {
  const float* ts = (const float*)d_in[0];
  const float* y0 = (const float*)d_in[1];
  const float* W1 = (const float*)d_in[2];
  const float* b1 = (const float*)d_in[3];
  const float* W2 = (const float*)d_in[4];
  const float* b2 = (const float*)d_in[5];
  const float* W3 = (const float*)d_in[6];
  const float* b3 = (const float*)d_in[7];
  const float* W4 = (const float*)d_in[8];
  const float* b4 = (const float*)d_in[9];

  ode_kernel<<<NB / 32, 256, 0, stream>>>(ts, y0, W1, b1, W2, b2, W3, b3, W4, b4,
                                          (float*)d_out);
}

// Round 5
// 64.622 us; speedup vs baseline: 2.9439x; 2.9439x over previous
//
#include <hip/hip_runtime.h>

#define NB 8192
#define NT 64
#define FCAP 5.0f

typedef unsigned int u32;
typedef float f32x4 __attribute__((ext_vector_type(4)));
typedef __bf16 bf16x8 __attribute__((ext_vector_type(8)));
typedef u32 u32x4 __attribute__((ext_vector_type(4)));
typedef u32 u32x2 __attribute__((ext_vector_type(2)));

static __device__ __forceinline__ u32 pk2(float lo, float hi) {
  u32 r;
  asm("v_cvt_pk_bf16_f32 %0, %1, %2" : "=v"(r) : "v"(lo), "v"(hi));
  return r;
}
static __device__ __forceinline__ float clipc(float a) { return fminf(fmaxf(a, -FCAP), FCAP); }

// pack 8 consecutive f32 into one bf16x8 fragment (RNE)
static __device__ __forceinline__ bf16x8 mkfrag(const float* __restrict__ p) {
  f32x4 a = *(const f32x4*)p, b = *(const f32x4*)(p + 4);
  u32x4 wv = {pk2(a[0], a[1]), pk2(a[2], a[3]), pk2(b[0], b[1]), pk2(b[2], b[3])};
  return __builtin_bit_cast(bf16x8, wv);
}

#define MFMA16(A, B, C) __builtin_amdgcn_mfma_f32_16x16x32_bf16(A, B, C, 0, 0, 0)

// 16x16x32 bf16 layouts (16x16 C verified m89; A/B mirror the round-3-verified
// 32x32 pattern):
//   A: row = lane&15, k = 32*kt + 8*(lane>>4) + e
//   B: col = lane&15, k = 32*kt + 8*(lane>>4) + e
//   C: col = lane&15, row = 4*(lane>>4) + reg
// LDS h-buffer: buf[col][kpair] (u32 = bf16x2 of rows 2kp,2kp+1), row stride 68
// words (breaks pow2). C regs (rows R0..R0+3, R0 even) pack to kpairs R0/2,
// R0/2+1 -> one ds_write_b64. B-frag for ktile kt = words [68c+16kt+4g .. +3]
// -> one ds_read_b128. Distribution over banks is uniform (8 lanes per 4-bank
// group = b128 floor).
#define LRELU4(C)                                                  \
  _Pragma("unroll") for (int r_ = 0; r_ < 4; ++r_) {               \
    C[r_] = fmaxf(C[r_], 0.01f * C[r_]);                           \
  }

// 512 WGs x 256 threads (2 WGs/CU, 2 waves/SIMD). Each WG: 16 particles.
// Wave wv owns hidden rows [32wv, 32wv+32) as two 16-row M-tiles.
__global__ __launch_bounds__(256, 2) void ode_kernel(
    const float* __restrict__ ts, const float* __restrict__ y0,
    const float* __restrict__ W1, const float* __restrict__ b1,
    const float* __restrict__ W2, const float* __restrict__ b2,
    const float* __restrict__ W3, const float* __restrict__ b3,
    const float* __restrict__ W4, const float* __restrict__ b4,
    float* __restrict__ out) {
  const int tid = threadIdx.x;
  const int wv = __builtin_amdgcn_readfirstlane(tid >> 6);  // wave 0..3
  const int l = tid & 63;
  const int g = l >> 4;   // lane group 0..3
  const int c = l & 15;   // particle col / A-row-local
  const int gp0 = blockIdx.x * 16;

  __shared__ alignas(16) u32 bufA[16 * 68];
  __shared__ alignas(16) u32 bufB[16 * 68];
  __shared__ alignas(16) float fbuf[16 * 8];  // [c][wv][2]

  // ---- A-fragments (one-time, f32 -> bf16 RNE) ----
  bf16x8 aW2[2][4], aW3[2][4];
#pragma unroll
  for (int mt = 0; mt < 2; ++mt) {
    const int R = 32 * wv + 16 * mt + c;
#pragma unroll
    for (int kt = 0; kt < 4; ++kt) {
      aW2[mt][kt] = mkfrag(W2 + R * 128 + 32 * kt + 8 * g);
      aW3[mt][kt] = mkfrag(W3 + R * 128 + 32 * kt + 8 * g);
    }
  }
  // L1: k0,k1 = W1 row, k2 = b1 (B supplies y1,y2,1)
  bf16x8 aW1[2];
#pragma unroll
  for (int mt = 0; mt < 2; ++mt) {
    const int R = 32 * wv + 16 * mt + c;
    u32x4 f = {0, 0, 0, 0};
    if (g == 0) {
      f[0] = pk2(W1[2 * R], W1[2 * R + 1]);
      f[1] = pk2(b1[R], 0.f);
    }
    aW1[mt] = __builtin_bit_cast(bf16x8, f);
  }
  // L4: A rows 0,1 = W4 over this wave's k-range [32wv, 32wv+32)
  bf16x8 aW4;
  {
    u32x4 f = {0, 0, 0, 0};
    if (c < 2) {
      const float* s = W4 + c * 128 + 32 * wv + 8 * g;
      f32x4 a = *(const f32x4*)s, b = *(const f32x4*)(s + 4);
      f = (u32x4){pk2(a[0], a[1]), pk2(a[2], a[3]), pk2(b[0], b[1]), pk2(b[2], b[3])};
    }
    aW4 = __builtin_bit_cast(bf16x8, f);
  }
  // b2/b3 as C-init registers: C row = 32wv + 16mt + 4g + reg
  f32x4 cb2[2], cb3[2];
#pragma unroll
  for (int mt = 0; mt < 2; ++mt) {
#pragma unroll
    for (int r = 0; r < 4; ++r) {
      const int row = 32 * wv + 16 * mt + 4 * g + r;
      cb2[mt][r] = b2[row];
      cb3[mt][r] = b3[row];
    }
  }
  const float b40 = b4[0], b41 = b4[1];

  // ---- state: all lanes track y for col c (uniform across g, wv) ----
  float y1 = y0[(gp0 + c) * 2];
  float y2 = y0[(gp0 + c) * 2 + 1];

  if (wv == 0 && g == 0) {
    float2 st = {clipc(y1), clipc(y2)};
    *(float2*)(out + (gp0 + c) * 2) = st;
  }

  const f32x4 zero4 = {0.f, 0.f, 0.f, 0.f};
  const int wbase = 68 * c + 16 * wv + 2 * g;  // write word base (M-tile 0)
  const int rbase = 68 * c + 4 * g;            // read word base (k-tile 0)

#pragma unroll 1
  for (int t = 0; t < NT - 1; ++t) {
    const float dt = ts[t + 1] - ts[t];

    // ---- layer 1 (bias fused: B k0=y1,k1=y2,k2=1) ----
    u32x4 byw = {0, 0, 0, 0};
    if (g == 0) {
      byw[0] = pk2(y1, y2);
      byw[1] = 0x3f80u;  // bf16(1.0) in lo half
    }
    const bf16x8 By = __builtin_bit_cast(bf16x8, byw);
    f32x4 C0 = MFMA16(aW1[0], By, zero4);
    f32x4 C1 = MFMA16(aW1[1], By, zero4);
    LRELU4(C0);
    LRELU4(C1);
    *(__shared__ u32x2*)&bufA[wbase]     = (u32x2){pk2(C0[0], C0[1]), pk2(C0[2], C0[3])};
    *(__shared__ u32x2*)&bufA[wbase + 8] = (u32x2){pk2(C1[0], C1[1]), pk2(C1[2], C1[3])};
    __syncthreads();

    // ---- layer 2 ----
    f32x4 D0 = cb2[0], D1 = cb2[1];
#pragma unroll
    for (int kt = 0; kt < 4; ++kt) {
      const bf16x8 q =
          __builtin_bit_cast(bf16x8, *(const __shared__ u32x4*)&bufA[rbase + 16 * kt]);
      D0 = MFMA16(aW2[0][kt], q, D0);
      D1 = MFMA16(aW2[1][kt], q, D1);
    }
    LRELU4(D0);
    LRELU4(D1);
    *(__shared__ u32x2*)&bufB[wbase]     = (u32x2){pk2(D0[0], D0[1]), pk2(D0[2], D0[3])};
    *(__shared__ u32x2*)&bufB[wbase + 8] = (u32x2){pk2(D1[0], D1[1]), pk2(D1[2], D1[3])};
    __syncthreads();

    // ---- layer 3 (h3 -> bufA; safe: all waves are past their L2 reads) ----
    f32x4 E0 = cb3[0], E1 = cb3[1];
#pragma unroll
    for (int kt = 0; kt < 4; ++kt) {
      const bf16x8 q =
          __builtin_bit_cast(bf16x8, *(const __shared__ u32x4*)&bufB[rbase + 16 * kt]);
      E0 = MFMA16(aW3[0][kt], q, E0);
      E1 = MFMA16(aW3[1][kt], q, E1);
    }
    LRELU4(E0);
    LRELU4(E1);
    *(__shared__ u32x2*)&bufA[wbase]     = (u32x2){pk2(E0[0], E0[1]), pk2(E0[2], E0[3])};
    *(__shared__ u32x2*)&bufA[wbase + 8] = (u32x2){pk2(E1[0], E1[1]), pk2(E1[2], E1[3])};

    // ---- layer 4: k-tile wv is self-owned -> no barrier, just lgkmcnt ----
    const bf16x8 q3 =
        __builtin_bit_cast(bf16x8, *(const __shared__ u32x4*)&bufA[rbase + 16 * wv]);
    f32x4 C4 = MFMA16(aW4, q3, zero4);
    if (g == 0)
      *(__shared__ float2*)&fbuf[c * 8 + wv * 2] = (float2){C4[0], C4[1]};
    __syncthreads();

    // ---- reduce 4 wave-partials + Euler update (uniform across lanes) ----
    const float4 pa = *(const __shared__ float4*)&fbuf[c * 8];
    const float4 pb = *(const __shared__ float4*)&fbuf[c * 8 + 4];
    const float f0 = b40 + pa.x + pa.z + pb.x + pb.z;
    const float f1v = b41 + pa.y + pa.w + pb.y + pb.w;
    y1 += dt * (f0 - y1);
    y2 += dt * (f1v - y2);

    if (wv == 0 && g == 0) {
      float2 st = {clipc(y1), clipc(y2)};
      *(float2*)(out + (t + 1) * (NB * 2) + (gp0 + c) * 2) = st;
    }
  }
}

extern "C" void kernel_launch(void* const* d_in, const int* in_sizes, int n_in,
                              void* d_out, int out_size, void* d_ws, size_t ws_size,
                              hipStream_t stream) {
  const float* ts = (const float*)d_in[0];
  const float* y0 = (const float*)d_in[1];
  const float* W1 = (const float*)d_in[2];
  const float* b1 = (const float*)d_in[3];
  const float* W2 = (const float*)d_in[4];
  const float* b2 = (const float*)d_in[5];
  const float* W3 = (const float*)d_in[6];
  const float* b3 = (const float*)d_in[7];
  const float* W4 = (const float*)d_in[8];
  const float* b4 = (const float*)d_in[9];

  ode_kernel<<<NB / 16, 256, 0, stream>>>(ts, y0, W1, b1, W2, b2, W3, b3, W4, b4,
                                          (float*)d_out);
}